// Round 2
// baseline (25.320 us; speedup 1.0000x reference)
//
#include <hip/hip_runtime.h>

#define IN_DIM 10
#define OUT_DIM 3
#define BLOCK 256
#define WPB 4            // waves per block
#define RPW 128          // rows per wave (2 per lane)

// ---- kernel A: proj = M^-1 @ W  (one wave, once) ----
__global__ void proj_setup_kernel(const float* __restrict__ W,
                                  const float* __restrict__ M,
                                  float* __restrict__ proj)
{
    const int t = threadIdx.x;
    const float a = M[0], b = M[1], c = M[2];
    const float d = M[3], e = M[4], f_ = M[5];
    const float g = M[6], h = M[7], i_ = M[8];
    const float A =  (e * i_ - f_ * h);
    const float B = -(d * i_ - f_ * g);
    const float C =  (d * h  - e  * g);
    const float det = a * A + b * B + c * C;
    float inv[3][3];
    // torch.isclose(det, 0, rtol=1e-5, atol=1e-8) -> |det| <= 1e-8
    if (fabsf(det) <= 1e-8f) {
        const float qn = __builtin_nanf("");
        #pragma unroll
        for (int o = 0; o < 3; ++o)
            #pragma unroll
            for (int k = 0; k < 3; ++k) inv[o][k] = qn;
    } else {
        const float r = 1.0f / det;
        inv[0][0] = A * r;
        inv[0][1] = (c * h  - b * i_) * r;
        inv[0][2] = (b * f_ - c * e ) * r;
        inv[1][0] = B * r;
        inv[1][1] = (a * i_ - c * g ) * r;
        inv[1][2] = (c * d  - a * f_) * r;
        inv[2][0] = C * r;
        inv[2][1] = (b * g  - a * h ) * r;
        inv[2][2] = (a * e  - b * d ) * r;
    }
    if (t < OUT_DIM * IN_DIM) {
        const int o = t / IN_DIM, j = t % IN_DIM;
        proj[t] = inv[o][0] * W[0 * IN_DIM + j]
                + inv[o][1] * W[1 * IN_DIM + j]
                + inv[o][2] * W[2 * IN_DIM + j];
    }
}

// ---- kernel B: barrier-free streaming y = x @ proj^T ----
__global__ __launch_bounds__(BLOCK) void simnet_stream(
    const float* __restrict__ x,
    const float* __restrict__ proj,
    float* __restrict__ out,
    long long batch)
{
    // wave-private LDS slices: no __syncthreads anywhere.
    __shared__ __align__(16) float s_in[WPB][RPW * IN_DIM];   // 4 x 1280 floats = 20 KB

    const int wv   = threadIdx.x >> 6;
    const int lane = threadIdx.x & 63;
    const long long tile = (long long)blockIdx.x * WPB + wv;
    const long long row0 = tile * RPW;
    if (row0 >= batch) return;

    // wave-uniform constant-offset loads -> s_load (SGPR-resident proj)
    float pj[OUT_DIM][IN_DIM];
    #pragma unroll
    for (int o = 0; o < OUT_DIM; ++o)
        #pragma unroll
        for (int j = 0; j < IN_DIM; ++j)
            pj[o][j] = proj[o * IN_DIM + j];

    float* sin_ = s_in[wv];

    if (row0 + RPW <= batch) {
        // ---- coalesced stage: 320 float4 per wave, 5 per lane ----
        const float4* src = reinterpret_cast<const float4*>(x + row0 * IN_DIM);
        float4* dst = reinterpret_cast<float4*>(sin_);
        #pragma unroll
        for (int k = 0; k < 5; ++k)
            dst[k * 64 + lane] = src[k * 64 + lane];
        // same-wave DS ordering + explicit drain before cross-lane read
        asm volatile("s_waitcnt lgkmcnt(0)" ::: "memory");

        // ---- compute 2 rows/lane from LDS (float2 reads, 8B aligned) ----
        float acc[2][OUT_DIM];
        #pragma unroll
        for (int r = 0; r < 2; ++r) {
            const int lr = lane + r * 64;
            const float2* s2 = reinterpret_cast<const float2*>(sin_ + lr * IN_DIM);
            const float2 a0 = s2[0], a1 = s2[1], a2 = s2[2], a3 = s2[3], a4 = s2[4];
            #pragma unroll
            for (int o = 0; o < OUT_DIM; ++o) {
                float s;
                s = a0.x * pj[o][0];
                s = fmaf(a0.y, pj[o][1], s);
                s = fmaf(a1.x, pj[o][2], s);
                s = fmaf(a1.y, pj[o][3], s);
                s = fmaf(a2.x, pj[o][4], s);
                s = fmaf(a2.y, pj[o][5], s);
                s = fmaf(a3.x, pj[o][6], s);
                s = fmaf(a3.y, pj[o][7], s);
                s = fmaf(a4.x, pj[o][8], s);
                s = fmaf(a4.y, pj[o][9], s);
                acc[r][o] = s;
            }
        }

        // ---- reuse front of wave slice for out staging (WAR safe: per-wave
        //      DS ops execute in order; all reads above precede these writes) ----
        #pragma unroll
        for (int r = 0; r < 2; ++r) {
            const int lr = lane + r * 64;
            #pragma unroll
            for (int o = 0; o < OUT_DIM; ++o)
                sin_[lr * OUT_DIM + o] = acc[r][o];   // stride 3: conflict-free
        }
        asm volatile("s_waitcnt lgkmcnt(0)" ::: "memory");

        // ---- coalesced store: 96 float4 per wave ----
        float4* od = reinterpret_cast<float4*>(out + row0 * OUT_DIM);
        const float4* so4 = reinterpret_cast<const float4*>(sin_);
        od[lane] = so4[lane];
        if (lane < 32) od[64 + lane] = so4[64 + lane];
    } else {
        // partial tail tile (not taken at BATCH=2e6): scalar fallback
        #pragma unroll
        for (int r = 0; r < 2; ++r) {
            const long long row = row0 + lane + r * 64;
            if (row < batch) {
                float s0 = 0.f, s1 = 0.f, s2v = 0.f;
                const float* xr = x + row * IN_DIM;
                #pragma unroll
                for (int j = 0; j < IN_DIM; ++j) {
                    const float v = xr[j];
                    s0  = fmaf(v, pj[0][j], s0);
                    s1  = fmaf(v, pj[1][j], s1);
                    s2v = fmaf(v, pj[2][j], s2v);
                }
                out[row * OUT_DIM + 0] = s0;
                out[row * OUT_DIM + 1] = s1;
                out[row * OUT_DIM + 2] = s2v;
            }
        }
    }
}

extern "C" void kernel_launch(void* const* d_in, const int* in_sizes, int n_in,
                              void* d_out, int out_size, void* d_ws, size_t ws_size,
                              hipStream_t stream) {
    const float* x = (const float*)d_in[0];
    const float* W = (const float*)d_in[1];
    const float* M = (const float*)d_in[2];
    float* out  = (float*)d_out;
    float* proj = (float*)d_ws;                 // 30 floats of scratch

    const long long batch = (long long)in_sizes[0] / IN_DIM;
    const long long n_tiles = (batch + RPW - 1) / RPW;        // 15625 at 2e6
    const int grid = (int)((n_tiles + WPB - 1) / WPB);        // 3907

    proj_setup_kernel<<<1, 64, 0, stream>>>(W, M, proj);
    simnet_stream<<<grid, BLOCK, 0, stream>>>(x, proj, out, batch);
}

// Round 3
// 20.360 us; speedup vs baseline: 1.2436x; 1.2436x over previous
//
#include <hip/hip_runtime.h>

#define IN_DIM 10
#define OUT_DIM 3
#define BLOCK 256

// Each thread owns 2 consecutive rows = 80 B = 5 aligned float4 loads,
// and writes 6 floats = 3 aligned float2 stores. No LDS, no barriers.
__global__ __launch_bounds__(BLOCK, 6) void simnet_direct(
    const float* __restrict__ x,
    const float* __restrict__ W,
    const float* __restrict__ M,
    float* __restrict__ out,
    long long batch)
{
    const long long npairs = batch >> 1;     // batch = 2e6 -> 1e6 pairs
    const long long p = (long long)blockIdx.x * BLOCK + threadIdx.x;
    if (p >= npairs) return;

    // ---- issue x loads first: independent of proj, latency overlapped ----
    const float4* xv = reinterpret_cast<const float4*>(x) + 5 * p;
    const float4 v0 = xv[0];
    const float4 v1 = xv[1];
    const float4 v2 = xv[2];
    const float4 v3 = xv[3];
    const float4 v4 = xv[4];

    // ---- wave-uniform: inv(M) via adjugate, proj = inv @ W ----
    const float a = M[0], b = M[1], c = M[2];
    const float d = M[3], e = M[4], f_ = M[5];
    const float g = M[6], h = M[7], i_ = M[8];
    const float A =  (e * i_ - f_ * h);
    const float B = -(d * i_ - f_ * g);
    const float C =  (d * h  - e  * g);
    const float det = a * A + b * B + c * C;
    float inv[3][3];
    // torch.isclose(det, 0, rtol=1e-5, atol=1e-8) -> |det| <= 1e-8
    if (fabsf(det) <= 1e-8f) {
        const float qn = __builtin_nanf("");
        #pragma unroll
        for (int o = 0; o < 3; ++o)
            #pragma unroll
            for (int k = 0; k < 3; ++k) inv[o][k] = qn;
    } else {
        const float r = 1.0f / det;
        inv[0][0] = A * r;
        inv[0][1] = (c * h  - b * i_) * r;
        inv[0][2] = (b * f_ - c * e ) * r;
        inv[1][0] = B * r;
        inv[1][1] = (a * i_ - c * g ) * r;
        inv[1][2] = (c * d  - a * f_) * r;
        inv[2][0] = C * r;
        inv[2][1] = (b * g  - a * h ) * r;
        inv[2][2] = (a * e  - b * d ) * r;
    }
    float pj[OUT_DIM][IN_DIM];
    #pragma unroll
    for (int o = 0; o < OUT_DIM; ++o)
        #pragma unroll
        for (int j = 0; j < IN_DIM; ++j)
            pj[o][j] = inv[o][0] * W[0 * IN_DIM + j]
                     + inv[o][1] * W[1 * IN_DIM + j]
                     + inv[o][2] * W[2 * IN_DIM + j];

    // ---- rows: r0 = v0.xyzw v1.xyzw v2.xy ; r1 = v2.zw v3.xyzw v4.xyzw ----
    const float r0j[IN_DIM] = { v0.x, v0.y, v0.z, v0.w,
                                v1.x, v1.y, v1.z, v1.w,
                                v2.x, v2.y };
    const float r1j[IN_DIM] = { v2.z, v2.w,
                                v3.x, v3.y, v3.z, v3.w,
                                v4.x, v4.y, v4.z, v4.w };
    float y0[OUT_DIM], y1[OUT_DIM];
    #pragma unroll
    for (int o = 0; o < OUT_DIM; ++o) {
        float s0 = r0j[0] * pj[o][0];
        float s1 = r1j[0] * pj[o][0];
        #pragma unroll
        for (int j = 1; j < IN_DIM; ++j) {
            s0 = fmaf(r0j[j], pj[o][j], s0);
            s1 = fmaf(r1j[j], pj[o][j], s1);
        }
        y0[o] = s0;
        y1[o] = s1;
    }

    // ---- 3 aligned float2 stores (24 B per pair) ----
    float2* o2 = reinterpret_cast<float2*>(out) + 3 * p;
    o2[0] = make_float2(y0[0], y0[1]);
    o2[1] = make_float2(y0[2], y1[0]);
    o2[2] = make_float2(y1[1], y1[2]);
}

// Generic tail: handles a possible final odd row (not taken at batch = 2e6).
__global__ void simnet_tail(const float* __restrict__ x,
                            const float* __restrict__ W,
                            const float* __restrict__ M,
                            float* __restrict__ out,
                            long long batch)
{
    if (threadIdx.x != 0 || (batch & 1LL) == 0) return;
    const long long row = batch - 1;
    const float a = M[0], b = M[1], c = M[2];
    const float d = M[3], e = M[4], f_ = M[5];
    const float g = M[6], h = M[7], i_ = M[8];
    const float A =  (e * i_ - f_ * h);
    const float B = -(d * i_ - f_ * g);
    const float C =  (d * h  - e  * g);
    const float det = a * A + b * B + c * C;
    float inv[3][3];
    if (fabsf(det) <= 1e-8f) {
        const float qn = __builtin_nanf("");
        for (int o = 0; o < 3; ++o)
            for (int k = 0; k < 3; ++k) inv[o][k] = qn;
    } else {
        const float r = 1.0f / det;
        inv[0][0] = A * r;                  inv[0][1] = (c * h  - b * i_) * r;  inv[0][2] = (b * f_ - c * e ) * r;
        inv[1][0] = B * r;                  inv[1][1] = (a * i_ - c * g ) * r;  inv[1][2] = (c * d  - a * f_) * r;
        inv[2][0] = C * r;                  inv[2][1] = (b * g  - a * h ) * r;  inv[2][2] = (a * e  - b * d ) * r;
    }
    const float* xr = x + row * IN_DIM;
    for (int o = 0; o < OUT_DIM; ++o) {
        float s = 0.f;
        for (int j = 0; j < IN_DIM; ++j) {
            const float pj = inv[o][0] * W[0 * IN_DIM + j]
                           + inv[o][1] * W[1 * IN_DIM + j]
                           + inv[o][2] * W[2 * IN_DIM + j];
            s = fmaf(xr[j], pj, s);
        }
        out[row * OUT_DIM + o] = s;
    }
}

extern "C" void kernel_launch(void* const* d_in, const int* in_sizes, int n_in,
                              void* d_out, int out_size, void* d_ws, size_t ws_size,
                              hipStream_t stream) {
    const float* x = (const float*)d_in[0];
    const float* W = (const float*)d_in[1];
    const float* M = (const float*)d_in[2];
    float* out = (float*)d_out;
    const long long batch = (long long)in_sizes[0] / IN_DIM;
    const long long npairs = batch >> 1;
    const int grid = (int)((npairs + BLOCK - 1) / BLOCK);
    simnet_direct<<<grid, BLOCK, 0, stream>>>(x, W, M, out, batch);
    if (batch & 1LL)
        simnet_tail<<<1, 64, 0, stream>>>(x, W, M, out, batch);
}